// Round 14
// baseline (40.854 us; speedup 1.0000x reference)
//
#include <hip/hip_runtime.h>
#include <stdint.h>

#define NB 256
#define NQ 900
#define NC 256
#define TOPK 100
#define QC (NQ * NC)      // 230400
#define NBINS_S 4096
#define CAP 4096
#define FCAP 512
#define KS 25
#define SHIFT 18
#define RT 272            // eobj-rank prefetch target (active rows ~220 < 272)
#define RLCAP 288         // rowlist cap = 16 waves x 18 regs

// R13 structure (validated, absmax 0) + ONE change: B1 rows are PREFETCHED
// into registers before the score threshold is known. Active set is an eobj
// threshold, so a top-RT-eobj superset is computable right after eobj;
// 18 float4/lane in flight hide the ~280 scattered row loads under the A1
// histogram + walks. B1 becomes register compare + append. Rows not
// prefetched (cap/low-thr) take a remainder global scan. Candidate SET is
// unchanged (order-independent selection) -> output identical; fallback
// (binary-search full rescan) keeps exactness unconditional.

__device__ __forceinline__ float fastsig(float x) {
    return __builtin_amdgcn_rcpf(1.0f + __expf(-x));
}

__global__ __launch_bounds__(1024, 1)
void postproc_kernel(const float* __restrict__ logits,
                     const float* __restrict__ obj,
                     const float* __restrict__ pboxes,
                     const float* __restrict__ tsz,
                     float* __restrict__ out)
{
    const int b = blockIdx.x;
    const int tid = threadIdx.x;
    const int wid = tid >> 6;
    const int lane = tid & 63;

    __shared__ unsigned int pool[NBINS_S];    // eobj hist -> shist -> fine -> fb/fi
    __shared__ float eobj[NQ];
    __shared__ float xthrRow[NQ];
    __shared__ unsigned int cbits[CAP];
    __shared__ int cidx[CAP];
    __shared__ unsigned short remQ[NQ];
    __shared__ unsigned short rowlist[RLCAP];
    __shared__ unsigned char rowPref[NQ];
    __shared__ unsigned int part[1024];
    __shared__ unsigned int part2[32];
    __shared__ int s_bin, s_cnt, s_nrl, s_nrem, s_c2;
    __shared__ int s_cut, s_dig, s_above, s_nfin;

    const float4* lg4 = (const float4*)(logits + (size_t)b * QC);

    // ---- issue A1 sample-row loads FIRST (static addresses, oldest in queue) ----
    float4 smp[4];
    #pragma unroll
    for (int r = 0; r < 4; ++r) {
        int j = wid + 16 * r;
        if (j < 56) smp[r] = lg4[((j * 16 + 8) << 6) + lane];
    }

    // ---- init + eobj ----
    for (int i = tid; i < NBINS_S; i += 1024) pool[i] = 0;
    if (tid == 0) { s_cnt = 0; s_nrl = 0; s_nrem = 0; }
    if (tid < NQ) { eobj[tid] = expf(-obj[b * NQ + tid]); rowPref[tid] = 0; }
    __syncthreads();

    // ---- eobj-rank histogram (bin = (bits>>15) - 0x7D00, ~512 live bins) ----
    if (tid < NQ) {
        unsigned eb = __float_as_uint(eobj[tid]);
        int bin = (int)(eb >> 15) - 0x7D00;
        bin = min(4095, max(0, bin));
        atomicAdd(&pool[bin], 1u);
    }
    __syncthreads();

    // ---- walk: max bin with suffix >= RT ----
    {
        unsigned int sum = 0;
        #pragma unroll
        for (int j = 0; j < 4; ++j) sum += pool[tid * 4 + j];
        part[tid] = sum;
    }
    __syncthreads();
    if (tid < 32) {
        unsigned int s2 = 0;
        #pragma unroll
        for (int j = 0; j < 32; ++j) s2 += part[tid * 32 + j];
        part2[tid] = s2;
    }
    __syncthreads();
    if (tid == 0) {
        int cum = 0;
        int sc = 31;
        while (sc > 0 && cum + (int)part2[sc] < RT) { cum += (int)part2[sc]; --sc; }
        int pc = sc * 32 + 31, plo = sc * 32;
        while (pc > plo && cum + (int)part[pc] < RT) { cum += (int)part[pc]; --pc; }
        int bin = pc * 4 + 3, blo = pc * 4;
        while (bin > blo && cum + (int)pool[bin] < RT) { cum += (int)pool[bin]; --bin; }
        s_bin = bin;
    }
    __syncthreads();
    const unsigned rowEdge = ((unsigned)(s_bin + 0x7D00)) << 15;

    // ---- rowlist (prefetch set) + zero pool for A1 ----
    if (tid < NQ && __float_as_uint(eobj[tid]) >= rowEdge) {
        int p = atomicAdd(&s_nrl, 1);
        if (p < RLCAP) { rowlist[p] = (unsigned short)tid; rowPref[tid] = 1; }
    }
    for (int i = tid; i < NBINS_S; i += 1024) pool[i] = 0;
    __syncthreads();
    const int nrl = min(s_nrl, RLCAP);

    // ---- issue prefetch loads (18 rows/wave in flight; land under A1+walks) ----
    float4 pre[18];
    #pragma unroll
    for (int r = 0; r < 18; ++r) {
        int idx = wid + 16 * r;
        if (idx < nrl) {
            int q = rowlist[idx];
            pre[r] = lg4[(q << 6) + lane];
        }
    }

    // ---- A1: sampled coarse histogram from smp registers ----
    #pragma unroll
    for (int r = 0; r < 4; ++r) {
        int j = wid + 16 * r;
        if (j < 56 && lane < 60) {
            int q = j * 16 + 8;
            float eo = eobj[q];
            float4 v = smp[r];
            atomicAdd(&pool[__float_as_uint(eo * fastsig(v.x)) >> SHIFT], 1u);
            atomicAdd(&pool[__float_as_uint(eo * fastsig(v.y)) >> SHIFT], 1u);
            atomicAdd(&pool[__float_as_uint(eo * fastsig(v.z)) >> SHIFT], 1u);
            atomicAdd(&pool[__float_as_uint(eo * fastsig(v.w)) >> SHIFT], 1u);
        }
    }
    __syncthreads();

    // ---- walk: threshold bin ----
    {
        unsigned int sum = 0;
        #pragma unroll
        for (int j = 0; j < 4; ++j) sum += pool[tid * 4 + j];
        part[tid] = sum;
    }
    __syncthreads();
    if (tid < 32) {
        unsigned int s2 = 0;
        #pragma unroll
        for (int j = 0; j < 32; ++j) s2 += part[tid * 32 + j];
        part2[tid] = s2;
    }
    __syncthreads();
    if (tid == 0) {
        int cum = 0;
        int sc = 31;
        while (sc > 0 && cum + (int)part2[sc] < KS) { cum += (int)part2[sc]; --sc; }
        int pc = sc * 32 + 31, plo = sc * 32;
        while (pc > plo && cum + (int)part[pc] < KS) { cum += (int)part[pc]; --pc; }
        int bin = pc * 4 + 3, blo = pc * 4;
        while (bin > blo && cum + (int)pool[bin] < KS) { cum += (int)pool[bin]; --bin; }
        s_bin = bin;
    }
    __syncthreads();
    unsigned int thrBits = (unsigned int)s_bin << SHIFT;
    const float thrF = __uint_as_float(thrBits);

    // fine-hist shift: smallest FS with (range >> FS) < 4096
    const unsigned rangeSel = 0x3F800000u - thrBits;
    int FS = 0;
    if ((int)rangeSel >= 4096) { int hb = 31 - __builtin_clz(rangeSel); FS = hb - 11; }

    // ---- per-row logit threshold for active rows + remainder list ----
    if (tid < NQ && __float_as_uint(eobj[tid]) >= thrBits) {
        float t = thrF / eobj[tid];            // in (0, 1]
        float r = t / (1.0f - t);              // inf when t == 1 (no candidates)
        xthrRow[tid] = logf(r) - 0.01f;        // conservative stage threshold
        if (!rowPref[tid]) {
            int p = atomicAdd(&s_nrem, 1);
            remQ[p] = (unsigned short)tid;
        }
    }
    for (int i = tid; i < NBINS_S; i += 1024) pool[i] = 0;   // zero for fine hist
    __syncthreads();

    // ---- pass B1: register compare-only prefilter ----
    #pragma unroll
    for (int r = 0; r < 18; ++r) {
        int idx = wid + 16 * r;
        if (idx < nrl) {
            int q = rowlist[idx];
            if (__float_as_uint(eobj[q]) >= thrBits) {
                float xt = xthrRow[q];
                if (lane < 60) {
                    float4 v = pre[r];
                    #pragma unroll
                    for (int j2 = 0; j2 < 4; ++j2) {
                        float x = (j2 == 0) ? v.x : (j2 == 1) ? v.y : (j2 == 2) ? v.z : v.w;
                        if (x >= xt) {
                            int p = atomicAdd(&s_cnt, 1);
                            if (p < CAP) {
                                cbits[p] = __float_as_uint(x);
                                cidx[p] = (q << 8) + (lane << 2) + j2;
                            }
                        }
                    }
                }
            }
        }
    }
    // ---- remainder: active rows not prefetched (normally none) ----
    {
        const int nrem = s_nrem;
        for (int j = wid; j < nrem; j += 16) {
            int q = remQ[j];
            float xt = xthrRow[q];
            if (lane < 60) {
                float4 v = lg4[(q << 6) + lane];
                #pragma unroll
                for (int j2 = 0; j2 < 4; ++j2) {
                    float x = (j2 == 0) ? v.x : (j2 == 1) ? v.y : (j2 == 2) ? v.z : v.w;
                    if (x >= xt) {
                        int p = atomicAdd(&s_cnt, 1);
                        if (p < CAP) {
                            cbits[p] = __float_as_uint(x);
                            cidx[p] = (q << 8) + (lane << 2) + j2;
                        }
                    }
                }
            }
        }
    }
    __syncthreads();
    const int npreRaw = s_cnt;
    const int npre = min(npreRaw, CAP);

    // pull my staged elements into registers (static indexing; frees cbits/cidx)
    int myN = 0;
    int midx0 = 0, midx1 = 0, midx2 = 0, midx3 = 0;
    float mlog0 = 0.f, mlog1 = 0.f, mlog2 = 0.f, mlog3 = 0.f;
    {
        int i = tid;
        if (i < npre) { midx0 = cidx[i]; mlog0 = __uint_as_float(cbits[i]); myN = 1; i += 1024; }
        if (i < npre) { midx1 = cidx[i]; mlog1 = __uint_as_float(cbits[i]); myN = 2; i += 1024; }
        if (i < npre) { midx2 = cidx[i]; mlog2 = __uint_as_float(cbits[i]); myN = 3; i += 1024; }
        if (i < npre) { midx3 = cidx[i]; mlog3 = __uint_as_float(cbits[i]); myN = 4; }
    }
    __syncthreads();
    if (tid == 0) s_cnt = 0;
    __syncthreads();

    // ---- pass B2: dense PRECISE rescore (defines outputs) + fine histogram ----
    #pragma unroll
    for (int k = 0; k < 4; ++k) {
        if (k < myN) {
            float x  = (k == 0) ? mlog0 : (k == 1) ? mlog1 : (k == 2) ? mlog2 : mlog3;
            int  idx = (k == 0) ? midx0 : (k == 1) ? midx1 : (k == 2) ? midx2 : midx3;
            float eo = eobj[idx >> 8];
            float s = eo * (1.0f / (1.0f + expf(-x)));
            unsigned bits = __float_as_uint(s);
            if (bits >= thrBits) {
                int p = atomicAdd(&s_cnt, 1);
                if (p < CAP) {
                    cbits[p] = bits;
                    cidx[p] = idx;
                    atomicAdd(&pool[(bits - thrBits) >> FS], 1u);
                }
            }
        }
    }
    __syncthreads();
    int M = s_cnt;
    const bool fbUsed = (M < TOPK || npreRaw > CAP);

    // ---- fallback (exact, any data): fires on shortfall OR staging overflow ----
    if (fbUsed) {
        int lo = 0, hi = NBINS_S - 1;
        while (lo < hi) {
            int mid = (lo + hi + 1) >> 1;
            unsigned int tb = (unsigned int)mid << SHIFT;
            if (tid == 0) s_c2 = 0;
            __syncthreads();
            int local = 0;
            for (int j = wid; j < NQ; j += 16) {
                if (__float_as_uint(eobj[j]) >= tb && lane < 60) {
                    float eo = eobj[j];
                    float4 v = lg4[(j << 6) + lane];
                    local += (__float_as_uint(eo * (1.0f / (1.0f + expf(-v.x)))) >= tb);
                    local += (__float_as_uint(eo * (1.0f / (1.0f + expf(-v.y)))) >= tb);
                    local += (__float_as_uint(eo * (1.0f / (1.0f + expf(-v.z)))) >= tb);
                    local += (__float_as_uint(eo * (1.0f / (1.0f + expf(-v.w)))) >= tb);
                }
            }
            atomicAdd(&s_c2, local);
            __syncthreads();
            if (s_c2 >= TOPK) lo = mid; else hi = mid - 1;
            __syncthreads();
        }
        unsigned int tb = (unsigned int)lo << SHIFT;
        thrBits = tb;
        if (tid == 0) s_cnt = 0;
        __syncthreads();
        for (int j = wid; j < NQ; j += 16) {
            if (__float_as_uint(eobj[j]) >= tb && lane < 60) {
                float eo = eobj[j];
                float4 v = lg4[(j << 6) + lane];
                #pragma unroll
                for (int j2 = 0; j2 < 4; ++j2) {
                    float x = (j2 == 0) ? v.x : (j2 == 1) ? v.y : (j2 == 2) ? v.z : v.w;
                    float s = eo * (1.0f / (1.0f + expf(-x)));
                    unsigned int bits = __float_as_uint(s);
                    if (bits >= tb) {
                        int p = atomicAdd(&s_cnt, 1);
                        if (p < CAP) {
                            cbits[p] = bits;
                            cidx[p] = (j << 8) + (lane << 2) + j2;
                        }
                    }
                }
            }
        }
        __syncthreads();
        M = s_cnt;
    }
    M = min(M, CAP);

    // ---- selection: fine-histogram cut (normal) or radix (rare) ----
    unsigned selBits = 0;
    bool haveSel = false;

    if (!fbUsed) {
        {
            unsigned int sum = 0;
            #pragma unroll
            for (int j = 0; j < 4; ++j) sum += pool[tid * 4 + j];
            part[tid] = sum;
        }
        __syncthreads();
        if (tid < 32) {
            unsigned int s2 = 0;
            #pragma unroll
            for (int j = 0; j < 32; ++j) s2 += part[tid * 32 + j];
            part2[tid] = s2;
        }
        __syncthreads();
        if (tid == 0) {
            int cum = 0;
            int sc = 31;
            while (sc > 0 && cum + (int)part2[sc] < TOPK) { cum += (int)part2[sc]; --sc; }
            int pc = sc * 32 + 31, plo = sc * 32;
            while (pc > plo && cum + (int)part[pc] < TOPK) { cum += (int)part[pc]; --pc; }
            int bin = pc * 4 + 3, blo = pc * 4;
            while (bin > blo && cum + (int)pool[bin] < TOPK) { cum += (int)pool[bin]; --bin; }
            s_cut = bin;
        }
        __syncthreads();
        selBits = thrBits + ((unsigned)s_cut << FS);
        haveSel = true;

        unsigned int* fb = pool;
        int* fi = (int*)(pool + FCAP);
        if (tid == 0) s_nfin = 0;
        __syncthreads();
        for (int i = tid; i < M; i += 1024) {
            unsigned int bb = cbits[i];
            if (bb >= selBits) {
                int p = atomicAdd(&s_nfin, 1);
                if (p < FCAP) { fb[p] = bb; fi[p] = cidx[i]; }
            }
        }
        __syncthreads();
        if (s_nfin > FCAP) haveSel = false;
    }

    if (!haveSel) {
        // ---- radix-select: exact TOPK-th largest bits among cbits[0..M) ----
        unsigned int* rhist = part;
        unsigned int* rsuf  = part + 256;
        unsigned int prefixVal = 0;
        int need = TOPK;
        int startShift = 24;
        if ((thrBits >> 24) == 0x3Fu) { prefixVal = 0x3F000000u; startShift = 16; }
        for (int shift = startShift; shift >= 0; shift -= 8) {
            if (tid < 256) rhist[tid] = 0;
            __syncthreads();
            unsigned int pmask = (shift >= 24) ? 0u : (0xFFFFFFFFu << (shift + 8));
            for (int i = tid; i < M; i += 1024) {
                unsigned int bb = cbits[i];
                if ((bb & pmask) == (prefixVal & pmask))
                    atomicAdd(&rhist[(bb >> shift) & 255], 1u);
            }
            __syncthreads();
            if (tid < 64) {
                unsigned int h0 = rhist[tid * 4 + 0];
                unsigned int h1 = rhist[tid * 4 + 1];
                unsigned int h2 = rhist[tid * 4 + 2];
                unsigned int h3 = rhist[tid * 4 + 3];
                unsigned int loc = h0 + h1 + h2 + h3;
                unsigned int suf = loc;
                #pragma unroll
                for (int d = 1; d < 64; d <<= 1) {
                    unsigned int o = __shfl_down(suf, d);
                    suf += (tid + d < 64) ? o : 0u;
                }
                unsigned int above = suf - loc;
                rsuf[tid * 4 + 3] = above + h3;
                rsuf[tid * 4 + 2] = above + h3 + h2;
                rsuf[tid * 4 + 1] = above + h3 + h2 + h1;
                rsuf[tid * 4 + 0] = above + h3 + h2 + h1 + h0;
            }
            __syncthreads();
            if (tid < 256) {
                int sv = (int)rsuf[tid];
                int sa = (tid == 255) ? 0 : (int)rsuf[tid + 1];
                if (sv >= need && sa < need) { s_dig = tid; s_above = sa; }
            }
            __syncthreads();
            prefixVal |= ((unsigned int)s_dig) << shift;
            need -= s_above;
        }
        selBits = prefixVal;

        unsigned int* fb = pool;
        int* fi = (int*)(pool + FCAP);
        if (tid == 0) s_nfin = 0;
        __syncthreads();
        for (int i = tid; i < M; i += 1024) {
            unsigned int bb = cbits[i];
            if (bb >= selBits) {
                int p = atomicAdd(&s_nfin, 1);
                if (p < FCAP) { fb[p] = bb; fi[p] = cidx[i]; }
            }
        }
        __syncthreads();
    }
    const int n = min(s_nfin, FCAP);

    // ---- exact rank over survivors (desc bits, tie -> lower index) ----
    unsigned int* fb = pool;
    int* fi = (int*)(pool + FCAP);
    const float ih = tsz[b * 2 + 0];
    const float iw = tsz[b * 2 + 1];
    float* out_scores = out;
    float* out_labels = out + NB * TOPK;
    float* out_boxes  = out + 2 * NB * TOPK;

    for (int i = tid; i < n; i += 1024) {
        unsigned int mb = fb[i];
        int mi = fi[i];
        int rank = 0;
        for (int j = 0; j < n; ++j) {
            unsigned int ob = fb[j];
            int oi = fi[j];
            rank += (ob > mb) || (ob == mb && oi < mi);
        }
        if (rank < TOPK) {
            int q = mi >> 8;
            int c = mi & 255;
            out_scores[b * TOPK + rank] = __uint_as_float(mb);
            out_labels[b * TOPK + rank] = (float)c;
            const float* bp = pboxes + ((size_t)b * NQ + q) * 4;
            float cx = bp[0], cy = bp[1], w = bp[2], h = bp[3];
            float* dst = out_boxes + ((size_t)b * TOPK + rank) * 4;
            dst[0] = (cx - 0.5f * w) * iw;
            dst[1] = (cy - 0.5f * h) * ih;
            dst[2] = (cx + 0.5f * w) * iw;
            dst[3] = (cy + 0.5f * h) * ih;
        }
    }
}

extern "C" void kernel_launch(void* const* d_in, const int* in_sizes, int n_in,
                              void* d_out, int out_size, void* d_ws, size_t ws_size,
                              hipStream_t stream) {
    const float* logits = (const float*)d_in[0];
    const float* obj    = (const float*)d_in[1];
    const float* boxes  = (const float*)d_in[2];
    const float* tsz    = (const float*)d_in[3];
    float* out = (float*)d_out;
    hipLaunchKernelGGL(postproc_kernel, dim3(NB), dim3(1024), 0, stream,
                       logits, obj, boxes, tsz, out);
}

// Round 15
// 32.220 us; speedup vs baseline: 1.2680x; 1.2680x over previous
//
#include <hip/hip_runtime.h>
#include <stdint.h>

#define NB 256
#define NQ 900
#define NC 256
#define TOPK 100
#define QC (NQ * NC)      // 230400
#define NBINS_S 4096
#define CAP 4096
#define FCAP 512
#define KS 25
#define SHIFT 18

// R13 optimum (validated, absmax 0, 32.45 us) — reverted after R14's prefetch
// regression. Structure:
//  - sampled coarse histogram (fast math) -> threshold thrBits
//  - activeQ row skip (exact bound: score <= eobj) + per-row LOGIT threshold
//    xthr[q] = logf(t/(1-t)) - 0.01, t = thrF/eobj[q] (monotone-exact + margin)
//  - pass B1: compare-only prefilter, stages (logit, idx)
//  - pass B2: dense PRECISE rescore (byte-identical expression) -> candidates
//    + fused 4096-bin fine histogram over [thrBits, 1.0)
//  - selection: fine-hist walk cut (suffix >= 100) -> ~110 survivors
//    (radix-select kept as rare-path), exact O(n^2) rank, box epilogue
//  - binary-search fallback (full precise rescan) on shortfall/overflow:
//    exactness unconditional.

__device__ __forceinline__ float fastsig(float x) {
    return __builtin_amdgcn_rcpf(1.0f + __expf(-x));
}

__global__ __launch_bounds__(1024)
void postproc_kernel(const float* __restrict__ logits,
                     const float* __restrict__ obj,
                     const float* __restrict__ pboxes,
                     const float* __restrict__ tsz,
                     float* __restrict__ out)
{
    const int b = blockIdx.x;
    const int tid = threadIdx.x;
    const int wid = tid >> 6;
    const int lane = tid & 63;

    __shared__ unsigned int pool[NBINS_S];    // shist -> fine hist -> fb/fi
    __shared__ float eobj[NQ];
    __shared__ float xthrRow[NQ];
    __shared__ unsigned int cbits[CAP];
    __shared__ int cidx[CAP];
    __shared__ int activeQ[NQ];
    __shared__ unsigned int part[1024];       // walk scratch / radix rhist+rsuf
    __shared__ unsigned int part2[32];
    __shared__ int s_thrBin, s_cnt, s_nActive, s_c2;
    __shared__ int s_cut, s_dig, s_above, s_nfin;

    unsigned int* shist = pool;

    for (int i = tid; i < NBINS_S; i += 1024) shist[i] = 0;
    if (tid == 0) { s_cnt = 0; s_nActive = 0; }
    if (tid < NQ) eobj[tid] = expf(-obj[b * NQ + tid]);
    __syncthreads();

    const float4* lg4 = (const float4*)(logits + (size_t)b * QC);

    // ---- A1: sampled coarse histogram (56 rows, 1/16), wave per row ----
    for (int j = wid; j < 56; j += 16) {
        int q = j * 16 + 8;
        if (lane < 60) {
            float eo = eobj[q];
            float4 v = lg4[(q << 6) + lane];
            atomicAdd(&shist[__float_as_uint(eo * fastsig(v.x)) >> SHIFT], 1u);
            atomicAdd(&shist[__float_as_uint(eo * fastsig(v.y)) >> SHIFT], 1u);
            atomicAdd(&shist[__float_as_uint(eo * fastsig(v.z)) >> SHIFT], 1u);
            atomicAdd(&shist[__float_as_uint(eo * fastsig(v.w)) >> SHIFT], 1u);
        }
    }
    __syncthreads();

    // ---- walk: threshold bin (hierarchical reduce + serial walk) ----
    {
        unsigned int sum = 0;
        #pragma unroll
        for (int j = 0; j < 4; ++j) sum += shist[tid * 4 + j];
        part[tid] = sum;
    }
    __syncthreads();
    if (tid < 32) {
        unsigned int s2 = 0;
        #pragma unroll
        for (int j = 0; j < 32; ++j) s2 += part[tid * 32 + j];
        part2[tid] = s2;
    }
    __syncthreads();
    if (tid == 0) {
        int cum = 0;
        int sc = 31;
        while (sc > 0 && cum + (int)part2[sc] < KS) { cum += (int)part2[sc]; --sc; }
        int pc = sc * 32 + 31, plo = sc * 32;
        while (pc > plo && cum + (int)part[pc] < KS) { cum += (int)part[pc]; --pc; }
        int bin = pc * 4 + 3, blo = pc * 4;
        while (bin > blo && cum + (int)shist[bin] < KS) { cum += (int)shist[bin]; --bin; }
        s_thrBin = bin;
    }
    __syncthreads();
    unsigned int thrBits = (unsigned int)s_thrBin << SHIFT;
    const float thrF = __uint_as_float(thrBits);

    // fine-hist shift: smallest FS with (range >> FS) < 4096
    const unsigned rangeSel = 0x3F800000u - thrBits;
    int FS = 0;
    if ((int)rangeSel >= 4096) { int hb = 31 - __builtin_clz(rangeSel); FS = hb - 11; }

    // ---- active rows (exact bound: score <= eobj) + per-row logit threshold ----
    if (tid < NQ) {
        if (__float_as_uint(eobj[tid]) >= thrBits) {
            int p = atomicAdd(&s_nActive, 1);
            activeQ[p] = tid;
            float t = thrF / eobj[tid];            // in (0, 1]
            float r = t / (1.0f - t);              // inf when t == 1 (no candidates)
            xthrRow[tid] = logf(r) - 0.01f;        // conservative stage threshold
        }
    }
    for (int i = tid; i < NBINS_S; i += 1024) pool[i] = 0;
    __syncthreads();
    const int nA = s_nActive;

    // ---- pass B1: compare-only prefilter, stage (logit, idx) ----
    for (int j = wid; j < nA; j += 16) {
        int q = activeQ[j];
        float xt = xthrRow[q];
        if (lane < 60) {
            float4 v = lg4[(q << 6) + lane];
            #pragma unroll
            for (int j2 = 0; j2 < 4; ++j2) {
                float x = (j2 == 0) ? v.x : (j2 == 1) ? v.y : (j2 == 2) ? v.z : v.w;
                if (x >= xt) {
                    int p = atomicAdd(&s_cnt, 1);
                    if (p < CAP) {
                        cbits[p] = __float_as_uint(x);
                        cidx[p] = (q << 8) + (lane << 2) + j2;
                    }
                }
            }
        }
    }
    __syncthreads();
    const int npreRaw = s_cnt;
    const int npre = min(npreRaw, CAP);

    // pull my staged elements into registers (static indexing; frees cbits/cidx)
    int myN = 0;
    int midx0 = 0, midx1 = 0, midx2 = 0, midx3 = 0;
    float mlog0 = 0.f, mlog1 = 0.f, mlog2 = 0.f, mlog3 = 0.f;
    {
        int i = tid;
        if (i < npre) { midx0 = cidx[i]; mlog0 = __uint_as_float(cbits[i]); myN = 1; i += 1024; }
        if (i < npre) { midx1 = cidx[i]; mlog1 = __uint_as_float(cbits[i]); myN = 2; i += 1024; }
        if (i < npre) { midx2 = cidx[i]; mlog2 = __uint_as_float(cbits[i]); myN = 3; i += 1024; }
        if (i < npre) { midx3 = cidx[i]; mlog3 = __uint_as_float(cbits[i]); myN = 4; }
    }
    __syncthreads();
    if (tid == 0) s_cnt = 0;
    __syncthreads();

    // ---- pass B2: dense PRECISE rescore (defines outputs) + fine histogram ----
    #pragma unroll
    for (int k = 0; k < 4; ++k) {
        if (k < myN) {
            float x  = (k == 0) ? mlog0 : (k == 1) ? mlog1 : (k == 2) ? mlog2 : mlog3;
            int  idx = (k == 0) ? midx0 : (k == 1) ? midx1 : (k == 2) ? midx2 : midx3;
            float eo = eobj[idx >> 8];
            float s = eo * (1.0f / (1.0f + expf(-x)));
            unsigned bits = __float_as_uint(s);
            if (bits >= thrBits) {
                int p = atomicAdd(&s_cnt, 1);
                if (p < CAP) {
                    cbits[p] = bits;
                    cidx[p] = idx;
                    atomicAdd(&pool[(bits - thrBits) >> FS], 1u);
                }
            }
        }
    }
    __syncthreads();
    int M = s_cnt;
    const bool fbUsed = (M < TOPK || npreRaw > CAP);

    // ---- fallback (exact, any data): fires on shortfall OR staging overflow ----
    if (fbUsed) {
        int lo = 0, hi = NBINS_S - 1;
        while (lo < hi) {
            int mid = (lo + hi + 1) >> 1;
            unsigned int tb = (unsigned int)mid << SHIFT;
            if (tid == 0) s_c2 = 0;
            __syncthreads();
            int local = 0;
            for (int j = wid; j < NQ; j += 16) {
                if (__float_as_uint(eobj[j]) >= tb && lane < 60) {
                    float eo = eobj[j];
                    float4 v = lg4[(j << 6) + lane];
                    local += (__float_as_uint(eo * (1.0f / (1.0f + expf(-v.x)))) >= tb);
                    local += (__float_as_uint(eo * (1.0f / (1.0f + expf(-v.y)))) >= tb);
                    local += (__float_as_uint(eo * (1.0f / (1.0f + expf(-v.z)))) >= tb);
                    local += (__float_as_uint(eo * (1.0f / (1.0f + expf(-v.w)))) >= tb);
                }
            }
            atomicAdd(&s_c2, local);
            __syncthreads();
            if (s_c2 >= TOPK) lo = mid; else hi = mid - 1;
            __syncthreads();
        }
        unsigned int tb = (unsigned int)lo << SHIFT;
        thrBits = tb;
        if (tid == 0) s_cnt = 0;
        __syncthreads();
        for (int j = wid; j < NQ; j += 16) {
            if (__float_as_uint(eobj[j]) >= tb && lane < 60) {
                float eo = eobj[j];
                float4 v = lg4[(j << 6) + lane];
                #pragma unroll
                for (int j2 = 0; j2 < 4; ++j2) {
                    float x = (j2 == 0) ? v.x : (j2 == 1) ? v.y : (j2 == 2) ? v.z : v.w;
                    float s = eo * (1.0f / (1.0f + expf(-x)));
                    unsigned int bits = __float_as_uint(s);
                    if (bits >= tb) {
                        int p = atomicAdd(&s_cnt, 1);
                        if (p < CAP) {
                            cbits[p] = bits;
                            cidx[p] = (j << 8) + (lane << 2) + j2;
                        }
                    }
                }
            }
        }
        __syncthreads();
        M = s_cnt;
    }
    M = min(M, CAP);

    // ---- selection: fine-histogram cut (normal) or radix (rare) ----
    unsigned selBits = 0;
    bool haveSel = false;

    if (!fbUsed) {
        {
            unsigned int sum = 0;
            #pragma unroll
            for (int j = 0; j < 4; ++j) sum += pool[tid * 4 + j];
            part[tid] = sum;
        }
        __syncthreads();
        if (tid < 32) {
            unsigned int s2 = 0;
            #pragma unroll
            for (int j = 0; j < 32; ++j) s2 += part[tid * 32 + j];
            part2[tid] = s2;
        }
        __syncthreads();
        if (tid == 0) {
            int cum = 0;
            int sc = 31;
            while (sc > 0 && cum + (int)part2[sc] < TOPK) { cum += (int)part2[sc]; --sc; }
            int pc = sc * 32 + 31, plo = sc * 32;
            while (pc > plo && cum + (int)part[pc] < TOPK) { cum += (int)part[pc]; --pc; }
            int bin = pc * 4 + 3, blo = pc * 4;
            while (bin > blo && cum + (int)pool[bin] < TOPK) { cum += (int)pool[bin]; --bin; }
            s_cut = bin;
        }
        __syncthreads();
        selBits = thrBits + ((unsigned)s_cut << FS);
        haveSel = true;

        unsigned int* fb = pool;
        int* fi = (int*)(pool + FCAP);
        if (tid == 0) s_nfin = 0;
        __syncthreads();
        for (int i = tid; i < M; i += 1024) {
            unsigned int bb = cbits[i];
            if (bb >= selBits) {
                int p = atomicAdd(&s_nfin, 1);
                if (p < FCAP) { fb[p] = bb; fi[p] = cidx[i]; }
            }
        }
        __syncthreads();
        if (s_nfin > FCAP) haveSel = false;
    }

    if (!haveSel) {
        // ---- radix-select: exact TOPK-th largest bits among cbits[0..M) ----
        unsigned int* rhist = part;
        unsigned int* rsuf  = part + 256;
        unsigned int prefixVal = 0;
        int need = TOPK;
        int startShift = 24;
        if ((thrBits >> 24) == 0x3Fu) { prefixVal = 0x3F000000u; startShift = 16; }
        for (int shift = startShift; shift >= 0; shift -= 8) {
            if (tid < 256) rhist[tid] = 0;
            __syncthreads();
            unsigned int pmask = (shift >= 24) ? 0u : (0xFFFFFFFFu << (shift + 8));
            for (int i = tid; i < M; i += 1024) {
                unsigned int bb = cbits[i];
                if ((bb & pmask) == (prefixVal & pmask))
                    atomicAdd(&rhist[(bb >> shift) & 255], 1u);
            }
            __syncthreads();
            if (tid < 64) {
                unsigned int h0 = rhist[tid * 4 + 0];
                unsigned int h1 = rhist[tid * 4 + 1];
                unsigned int h2 = rhist[tid * 4 + 2];
                unsigned int h3 = rhist[tid * 4 + 3];
                unsigned int loc = h0 + h1 + h2 + h3;
                unsigned int suf = loc;
                #pragma unroll
                for (int d = 1; d < 64; d <<= 1) {
                    unsigned int o = __shfl_down(suf, d);
                    suf += (tid + d < 64) ? o : 0u;
                }
                unsigned int above = suf - loc;
                rsuf[tid * 4 + 3] = above + h3;
                rsuf[tid * 4 + 2] = above + h3 + h2;
                rsuf[tid * 4 + 1] = above + h3 + h2 + h1;
                rsuf[tid * 4 + 0] = above + h3 + h2 + h1 + h0;
            }
            __syncthreads();
            if (tid < 256) {
                int sv = (int)rsuf[tid];
                int sa = (tid == 255) ? 0 : (int)rsuf[tid + 1];
                if (sv >= need && sa < need) { s_dig = tid; s_above = sa; }
            }
            __syncthreads();
            prefixVal |= ((unsigned int)s_dig) << shift;
            need -= s_above;
        }
        selBits = prefixVal;

        unsigned int* fb = pool;
        int* fi = (int*)(pool + FCAP);
        if (tid == 0) s_nfin = 0;
        __syncthreads();
        for (int i = tid; i < M; i += 1024) {
            unsigned int bb = cbits[i];
            if (bb >= selBits) {
                int p = atomicAdd(&s_nfin, 1);
                if (p < FCAP) { fb[p] = bb; fi[p] = cidx[i]; }
            }
        }
        __syncthreads();
    }
    const int n = min(s_nfin, FCAP);

    // ---- exact rank over survivors (desc bits, tie -> lower index) ----
    unsigned int* fb = pool;
    int* fi = (int*)(pool + FCAP);
    const float ih = tsz[b * 2 + 0];
    const float iw = tsz[b * 2 + 1];
    float* out_scores = out;
    float* out_labels = out + NB * TOPK;
    float* out_boxes  = out + 2 * NB * TOPK;

    for (int i = tid; i < n; i += 1024) {
        unsigned int mb = fb[i];
        int mi = fi[i];
        int rank = 0;
        for (int j = 0; j < n; ++j) {
            unsigned int ob = fb[j];
            int oi = fi[j];
            rank += (ob > mb) || (ob == mb && oi < mi);
        }
        if (rank < TOPK) {
            int q = mi >> 8;
            int c = mi & 255;
            out_scores[b * TOPK + rank] = __uint_as_float(mb);
            out_labels[b * TOPK + rank] = (float)c;
            const float* bp = pboxes + ((size_t)b * NQ + q) * 4;
            float cx = bp[0], cy = bp[1], w = bp[2], h = bp[3];
            float* dst = out_boxes + ((size_t)b * TOPK + rank) * 4;
            dst[0] = (cx - 0.5f * w) * iw;
            dst[1] = (cy - 0.5f * h) * ih;
            dst[2] = (cx + 0.5f * w) * iw;
            dst[3] = (cy + 0.5f * h) * ih;
        }
    }
}

extern "C" void kernel_launch(void* const* d_in, const int* in_sizes, int n_in,
                              void* d_out, int out_size, void* d_ws, size_t ws_size,
                              hipStream_t stream) {
    const float* logits = (const float*)d_in[0];
    const float* obj    = (const float*)d_in[1];
    const float* boxes  = (const float*)d_in[2];
    const float* tsz    = (const float*)d_in[3];
    float* out = (float*)d_out;
    hipLaunchKernelGGL(postproc_kernel, dim3(NB), dim3(1024), 0, stream,
                       logits, obj, boxes, tsz, out);
}